// Round 7
// baseline (221.896 us; speedup 1.0000x reference)
//
#include <hip/hip_runtime.h>

typedef unsigned short u16;
typedef short short8 __attribute__((ext_vector_type(8)));
typedef float floatx4 __attribute__((ext_vector_type(4)));
typedef __bf16 bf16x2 __attribute__((ext_vector_type(2)));

#define MFMA16(a, b, c) __builtin_amdgcn_mfma_f32_16x16x32_bf16((a), (b), (c), 0, 0, 0)

// ---- g_ws byte offsets (256-aligned) ----
#define W1F_OFF   0u         // bf16[4096]
#define B1F_OFF   8192u      // f32[64]
#define W2F_OFF   8448u      // bf16[8192]
#define B2F_OFF   24832u     // f32[128]
#define WA0F_OFF  25344u     // bf16[8192]
#define BAF_OFF   41728u     // f32[64]
#define WA1F_OFF  41984u     // f32[64]
#define BA1F_OFF  42240u     // f32[1]
#define P_OFF     42496u     // f32[32*128*64]
#define Q_OFF     1091072u   // f32[32*128*64]
#define SC_OFF    2139648u   // f32[32*128*128]
#define WS_TOTAL  4236800u

__device__ __align__(256) char g_ws[WS_TOTAL];

__device__ __forceinline__ float bits2f(unsigned u) {
  union { unsigned i; float f; } v; v.i = u; return v.f;
}
__device__ __forceinline__ unsigned f2bits(float f) {
  union { float f; unsigned i; } v; v.f = f; return v.i;
}
__device__ __forceinline__ u16 f2bf(float f) {
  return (u16)((f2bits(f) + 0x8000u) >> 16);
}
// two fp32 -> relu -> packed bf16 pair. gfx950: 2 fmax + 1 v_cvt_pk_bf16_f32.
__device__ __forceinline__ unsigned pack2relu(float a, float b) {
#if __has_builtin(__builtin_amdgcn_cvt_pk_bf16_f32)
  union { bf16x2 h; unsigned u; } cv;
  cv.h = __builtin_amdgcn_cvt_pk_bf16_f32(fmaxf(a, 0.f), fmaxf(b, 0.f));
  return cv.u;
#else
  unsigned lo = (f2bits(fmaxf(a, 0.f)) + 0x8000u) >> 16;
  unsigned hi = (f2bits(fmaxf(b, 0.f)) + 0x8000u) & 0xffff0000u;
  return lo | hi;
#endif
}

// XOR-swizzled LDS addressing (u16 units), conflict-free per-pattern.
__device__ __forceinline__ int sw64(int row, int col) {   // 64-col rows
  return (row << 6) + ((((col >> 3) ^ (row & 7)) << 3) | (col & 7));
}
__device__ __forceinline__ int sw128(int row, int col) {  // 128-col rows
  return (row << 7) + ((((col >> 3) ^ (row & 7)) << 3) | (col & 7));
}

// ------------------------------------------------------------------
// k_pre: 513 blocks x 256.  (unchanged)
// ------------------------------------------------------------------
__global__ __launch_bounds__(256) void k_pre(
    const float* __restrict__ feat, const float* __restrict__ w0,
    const float* __restrict__ g0, const float* __restrict__ b0, const float* __restrict__ m0, const float* __restrict__ v0,
    const float* __restrict__ w1, const float* __restrict__ g1, const float* __restrict__ b1, const float* __restrict__ m1, const float* __restrict__ v1,
    const float* __restrict__ w2, const float* __restrict__ g2, const float* __restrict__ b2, const float* __restrict__ m2, const float* __restrict__ v2,
    const float* __restrict__ wa0, const float* __restrict__ ga, const float* __restrict__ ba, const float* __restrict__ ma, const float* __restrict__ va,
    const float* __restrict__ wa1, const float* __restrict__ ba1,
    const float* __restrict__ wsc, const float* __restrict__ gsc, const float* __restrict__ bsc, const float* __restrict__ msc, const float* __restrict__ vsc)
{
  __shared__ float smem[9600];
  const int t = threadIdx.x;
  char* ws = g_ws;
  const int blk = blockIdx.x;

  if (blk == 512) {
    float* fs1 = smem; float* fs2 = smem + 64; float* fsa = smem + 192;
    if (t < 64) {
      float s;
      s = g1[t] * rsqrtf(v1[t] + 1e-5f); fs1[t] = s; ((float*)(ws + B1F_OFF))[t] = b1[t] - m1[t] * s;
      s = ga[t] * rsqrtf(va[t] + 1e-5f); fsa[t] = s; ((float*)(ws + BAF_OFF))[t] = ba[t] - ma[t] * s;
      ((float*)(ws + WA1F_OFF))[t] = wa1[t];
    }
    if (t < 128) { float s = g2[t] * rsqrtf(v2[t] + 1e-5f); fs2[t] = s; ((float*)(ws + B2F_OFF))[t] = b2[t] - m2[t] * s; }
    if (t == 0) ((float*)(ws + BA1F_OFF))[0] = ba1[0];
    __syncthreads();
    u16* W1f = (u16*)(ws + W1F_OFF);
    u16* W2f = (u16*)(ws + W2F_OFF);
    u16* Wa0f = (u16*)(ws + WA0F_OFF);
    for (int i = t; i < 4096; i += 256) W1f[i]  = f2bf(fs1[i >> 6] * w1[i]);
    for (int i = t; i < 8192; i += 256) W2f[i]  = f2bf(fs2[i >> 6] * w2[i]);
    for (int i = t; i < 8192; i += 256) Wa0f[i] = f2bf(fsa[i >> 7] * wa0[i]);
    return;
  }

  const int sub = blk & 255;
  const int b = sub >> 3, n0 = (sub & 7) << 4;
  float* Xs  = smem;          // [64][20]
  float* Wsm = smem + 1280;

  {
    const int c = t >> 2, j = (t & 3) << 2;
    *(float4*)(Xs + c * 20 + j) = *(const float4*)(feat + b * 8192 + c * 128 + n0 + j);
  }

  if (blk < 256) {
    #pragma unroll
    for (int r = 0; r < 8; r++) {
      const int i = (r * 256 + t) * 4;
      float4 v = *(const float4*)(w0 + i);
      const int o = i >> 7, c = i & 127;
      float* d = Wsm + o * 129 + c;
      d[0] = v.x; d[1] = v.y; d[2] = v.z; d[3] = v.w;
    }
    __syncthreads();
    const int o = t & 63, nb = (t >> 6) << 2;
    const float s  = g0[o] * rsqrtf(v0[o] + 1e-5f);
    const float tt = b0[o] - m0[o] * s;
    const float* wr = Wsm + o * 129;
    float dA0=0.f,dA1=0.f,dA2=0.f,dA3=0.f,dB0=0.f,dB1=0.f,dB2=0.f,dB3=0.f;
    #pragma unroll
    for (int c = 0; c < 64; c++) {
      const float a = wr[c], e = wr[64 + c];
      const float4 x = *(const float4*)(Xs + c * 20 + nb);
      dA0 += a * x.x; dA1 += a * x.y; dA2 += a * x.z; dA3 += a * x.w;
      dB0 += e * x.x; dB1 += e * x.y; dB2 += e * x.z; dB3 += e * x.w;
    }
    float* Pp = (float*)(ws + P_OFF) + (b * 128 + n0 + nb) * 64 + o;
    float* Qp = (float*)(ws + Q_OFF) + (b * 128 + n0 + nb) * 64 + o;
    Pp[0]   = s * dB0; Pp[64]  = s * dB1; Pp[128] = s * dB2; Pp[192] = s * dB3;
    Qp[0]   = s * (dA0 - dB0) + tt; Qp[64]  = s * (dA1 - dB1) + tt;
    Qp[128] = s * (dA2 - dB2) + tt; Qp[192] = s * (dA3 - dB3) + tt;
  } else {
    #pragma unroll
    for (int r = 0; r < 8; r++) {
      const int i = (r * 256 + t) * 4;
      float4 v = *(const float4*)(wsc + i);
      const int o = i >> 6, c = i & 63;
      float* d = Wsm + o * 65 + c;
      d[0] = v.x; d[1] = v.y; d[2] = v.z; d[3] = v.w;
    }
    __syncthreads();
    const int o = t & 127, h = (t >> 7) << 3;
    const float s  = gsc[o] * rsqrtf(vsc[o] + 1e-5f);
    const float tt = bsc[o] - msc[o] * s;
    const float* wr = Wsm + o * 65;
    float d0=0.f,d1=0.f,d2=0.f,d3=0.f,d4=0.f,d5=0.f,d6=0.f,d7=0.f;
    #pragma unroll
    for (int c = 0; c < 64; c++) {
      const float a = wr[c];
      const float4 x0 = *(const float4*)(Xs + c * 20 + h);
      const float4 x1 = *(const float4*)(Xs + c * 20 + h + 4);
      d0 += a * x0.x; d1 += a * x0.y; d2 += a * x0.z; d3 += a * x0.w;
      d4 += a * x1.x; d5 += a * x1.y; d6 += a * x1.z; d7 += a * x1.w;
    }
    float* SCp = (float*)(ws + SC_OFF) + (b * 128 + n0 + h) * 128 + o;
    SCp[0]   = s * d0 + tt; SCp[128] = s * d1 + tt; SCp[256] = s * d2 + tt; SCp[384] = s * d3 + tt;
    SCp[512] = s * d4 + tt; SCp[640] = s * d5 + tt; SCp[768] = s * d6 + tt; SCp[896] = s * d7 + tt;
  }
}

// ------------------------------------------------------------------
// k_main R16: edge-HALF streaming + online softmax (flash-style).
// The chain L0->G1->G2->G3 is edge-parallel; process 64-edge halves
// through 24KB of LDS (R_A: H0h then H2h rows 32-63; R_B: H2h rows
// 0-31; R_C: H1h) -> 26.6KB total -> 6 blocks/CU (was 4 at 35.3KB).
// Softmax is computed redundantly by ALL waves (no wave0 serial
// section, no attws broadcast); fts accumulates unnormalized with
// running-max rescale between halves; weights fetched via __shfl.
// Per-thread MFMA/LDS totals identical to R12. Barriers 7 -> 10.
// A-hoisting kept at proven scale only (a1+a2=24 regs; a3 per half).
// ------------------------------------------------------------------
__global__ __launch_bounds__(256, 6) void k_main(float* __restrict__ out)
{
  __shared__ alignas(16) u16 buf[12288];   // R_A@0, R_B@4096, R_C@8192 (u16 idx)
  __shared__ float parts[4][128];          // G3 partials [wid][edge-in-half]; final fts partials

  const int blk = blockIdx.x, b = blk >> 7, n = blk & 127, t = threadIdx.x;
  const char* ws = g_ws;
  const float* Pb  = (const float*)(ws + P_OFF);
  const float* Qb  = (const float*)(ws + Q_OFF);
  const float* SCb = (const float*)(ws + SC_OFF);
  const u16*   W1f = (const u16*)(ws + W1F_OFF);
  const float* b1f = (const float*)(ws + B1F_OFF);
  const u16*   W2f = (const u16*)(ws + W2F_OFF);
  const float* b2f = (const float*)(ws + B2F_OFF);
  const u16*   Wa0f= (const u16*)(ws + WA0F_OFF);
  const float* baf = (const float*)(ws + BAF_OFF);
  const float* wa1f= (const float*)(ws + WA1F_OFF);
  const float  ba1v= *(const float*)(ws + BA1F_OFF);

  u16* RA = buf;           // 4096 u16: H0h, then H2h rows 32-63
  u16* RB = buf + 4096;    // 4096 u16: H2h rows 0-31
  u16* RC = buf + 8192;    // 4096 u16: H1h

  const int lane = t & 63, wid = t >> 6, quad = lane >> 4, l16 = lane & 15;
  const int koff = quad * 8;
  const int chg = t & 15, eg = t >> 4;     // fts: 8 ch x 4 edges per thread per half

  // hoisted A-fragments (proven scale: 24 VGPRs)
  const short8 a1w0 = *(const short8*)(W1f + (wid * 16 + l16) * 64 + koff);
  const short8 a1w1 = *(const short8*)(W1f + (wid * 16 + l16) * 64 + 32 + koff);
  const short8 a2w00 = *(const short8*)(W2f + (wid * 32 + l16) * 64 + koff);
  const short8 a2w01 = *(const short8*)(W2f + (wid * 32 + l16) * 64 + 32 + koff);
  const short8 a2w10 = *(const short8*)(W2f + (wid * 32 + 16 + l16) * 64 + koff);
  const short8 a2w11 = *(const short8*)(W2f + (wid * 32 + 16 + l16) * 64 + 32 + koff);

  // hoisted epilogue loads
  float scv = 0.f;
  if (t < 128) scv = SCb[blk * 128 + t];
  float* outp = out + ((b << 7) + (t & 127)) * 128 + n;

  // online-softmax state (per wave, identical across waves) + fts acc
  float mx_run = 0.f, s_run = 0.f;
  float fa[8];
  #pragma unroll
  for (int k = 0; k < 8; k++) fa[k] = 0.f;

  #pragma unroll
  for (int h = 0; h < 2; h++) {
    // ---- L0h: H0h[e][ch] = relu(Q[b,n] + P[b,j]) for 64 edges ----
    {
      const int k = t >> 2, q4 = t & 3;
      const int egl = h * 64 + k;
      const int j = (egl < 127) ? ((egl < n) ? egl : (egl + 1)) : n;
      const float4* pr = (const float4*)(Pb + ((b << 7) + j) * 64 + q4 * 16);
      const float4* qr = (const float4*)(Qb + blk * 64 + q4 * 16);
      float4 p0 = pr[0], p1 = pr[1], p2 = pr[2], p3 = pr[3];
      float4 q0 = qr[0], q1 = qr[1], q2 = qr[2], q3 = qr[3];
      uint4 s0, s1;
      s0.x = pack2relu(q0.x + p0.x, q0.y + p0.y);
      s0.y = pack2relu(q0.z + p0.z, q0.w + p0.w);
      s0.z = pack2relu(q1.x + p1.x, q1.y + p1.y);
      s0.w = pack2relu(q1.z + p1.z, q1.w + p1.w);
      s1.x = pack2relu(q2.x + p2.x, q2.y + p2.y);
      s1.y = pack2relu(q2.z + p2.z, q2.w + p2.w);
      s1.z = pack2relu(q3.x + p3.x, q3.y + p3.y);
      s1.w = pack2relu(q3.z + p3.z, q3.w + p3.w);
      *(uint4*)(RA + sw64(k, q4 * 16))     = s0;
      *(uint4*)(RA + sw64(k, q4 * 16 + 8)) = s1;
    }
    __syncthreads();                                   // (1h) H0h ready

    // ---- G1h: wave owns out-ch wid*16..+15; 4 edge-tiles ----
    {
      const int rr = wid * 16 + quad * 4;
      const float4 bb = *(const float4*)(b1f + rr);
      floatx4 binit; binit[0] = bb.x; binit[1] = bb.y; binit[2] = bb.z; binit[3] = bb.w;
      floatx4 acc[4];
      #pragma unroll
      for (int et = 0; et < 4; et++) acc[et] = binit;
      #pragma unroll
      for (int et = 0; et < 4; et++) {
        const int row = et * 16 + l16;
        short8 bf0 = *(const short8*)(RA + sw64(row, koff));
        short8 bf1 = *(const short8*)(RA + sw64(row, koff + 32));
        acc[et] = MFMA16(a1w0, bf0, acc[et]);
        acc[et] = MFMA16(a1w1, bf1, acc[et]);
      }
      #pragma unroll
      for (int et = 0; et < 4; et++) {
        uint2 sv;
        sv.x = pack2relu(acc[et][0], acc[et][1]);
        sv.y = pack2relu(acc[et][2], acc[et][3]);
        *(uint2*)(RC + sw64(et * 16 + l16, rr)) = sv;
      }
    }
    __syncthreads();                                   // (2h) H1h ready; H0h dead

    // ---- G2h: wave owns out-ch wid*32..+31; writes H2h (RB/RA) ----
    {
      const int r2 = wid * 32 + quad * 4;
      const float4 bba = *(const float4*)(b2f + r2);
      const float4 bbb = *(const float4*)(b2f + r2 + 16);
      floatx4 ia; ia[0] = bba.x; ia[1] = bba.y; ia[2] = bba.z; ia[3] = bba.w;
      floatx4 ib; ib[0] = bbb.x; ib[1] = bbb.y; ib[2] = bbb.z; ib[3] = bbb.w;
      floatx4 acc[2][4];
      #pragma unroll
      for (int et = 0; et < 4; et++) { acc[0][et] = ia; acc[1][et] = ib; }
      #pragma unroll
      for (int et = 0; et < 4; et++) {
        const int row = et * 16 + l16;
        short8 bf0 = *(const short8*)(RC + sw64(row, koff));
        short8 bf1 = *(const short8*)(RC + sw64(row, koff + 32));
        acc[0][et] = MFMA16(a2w00, bf0, acc[0][et]);
        acc[0][et] = MFMA16(a2w01, bf1, acc[0][et]);
        acc[1][et] = MFMA16(a2w10, bf0, acc[1][et]);
        acc[1][et] = MFMA16(a2w11, bf1, acc[1][et]);
      }
      #pragma unroll
      for (int m = 0; m < 2; m++) {
        const int cc = r2 + m * 16;
        #pragma unroll
        for (int et = 0; et < 4; et++) {
          uint2 sv;
          sv.x = pack2relu(acc[m][et][0], acc[m][et][1]);
          sv.y = pack2relu(acc[m][et][2], acc[m][et][3]);
          if (et < 2) *(uint2*)(RB + sw128(et * 16 + l16, cc)) = sv;
          else        *(uint2*)(RA + sw128((et - 2) * 16 + l16, cc)) = sv;
        }
      }
    }

    // a3 for this half (L1-hot; 16 VGPRs, proven-kept scale)
    short8 a3[4];
    #pragma unroll
    for (int ks = 0; ks < 4; ks++)
      a3[ks] = *(const short8*)(Wa0f + (wid * 16 + l16) * 128 + ks * 32 + koff);

    __syncthreads();                                   // (3h) H2h ready

    // ---- G3h: wave owns att-ch wid*16..+15; partial logits ----
    {
      const int rr = wid * 16 + quad * 4;
      const float4 bb = *(const float4*)(baf + rr);
      const float4 wv = *(const float4*)(wa1f + rr);
      floatx4 binit; binit[0] = bb.x; binit[1] = bb.y; binit[2] = bb.z; binit[3] = bb.w;
      #pragma unroll
      for (int et = 0; et < 4; et++) {
        const int row = et * 16 + l16;
        const u16* hb = (et < 2) ? RB : RA;
        const int rrow = row & 31;
        floatx4 ac = binit;
        #pragma unroll
        for (int ks = 0; ks < 4; ks++) {
          short8 bf = *(const short8*)(hb + sw128(rrow, koff + ks * 32));
          ac = MFMA16(a3[ks], bf, ac);
        }
        float p = wv.x * fmaxf(ac[0], 0.f) + wv.y * fmaxf(ac[1], 0.f)
                + wv.z * fmaxf(ac[2], 0.f) + wv.w * fmaxf(ac[3], 0.f);
        p += __shfl_xor(p, 16); p += __shfl_xor(p, 32);
        if (quad == 0) parts[wid][et * 16 + l16] = p;
      }
    }

    // ---- fts prefetch (H2h final): 4 rows into regs ----
    uint4 hv[4];
    #pragma unroll
    for (int i = 0; i < 4; i++) {
      const int e = eg * 4 + i;
      const u16* hb = (eg < 8) ? RB : RA;
      hv[i] = *(const uint4*)(hb + sw128(e & 31, chg * 8));
    }

    __syncthreads();                                   // (4h) partial logits ready

    // ---- softmax-h: ALL waves compute identically (lane = edge) ----
    {
      float a = parts[0][lane] + parts[1][lane] + parts[2][lane] + parts[3][lane] + ba1v;
      if (h == 1 && lane == 63) a = -1e30f;            // edge 127 dummy
      float mxh = a;
      #pragma unroll
      for (int off = 32; off >= 1; off >>= 1) mxh = fmaxf(mxh, __shfl_xor(mxh, off));
      const float mxn = (h == 0) ? mxh : fmaxf(mx_run, mxh);
      const float f   = (h == 0) ? 1.f : expf(mx_run - mxn);
      const float w   = expf(a - mxn);
      float sh = w;
      #pragma unroll
      for (int off = 32; off >= 1; off >>= 1) sh += __shfl_xor(sh, off);
      s_run = (h == 0) ? sh : s_run * f + sh;
      mx_run = mxn;

      // ---- fts-h: fa = fa*f + sum_e w[e]*H2h[e][ch] (regs only) ----
      if (h == 1) {
        #pragma unroll
        for (int k = 0; k < 8; k++) fa[k] *= f;
      }
      #pragma unroll
      for (int i = 0; i < 4; i++) {
        const float wv = __shfl(w, eg * 4 + i);
        uint4 v = hv[i];
        unsigned u;
        u = v.x; fa[0] += wv * bits2f(u << 16); fa[1] += wv * bits2f(u & 0xffff0000u);
        u = v.y; fa[2] += wv * bits2f(u << 16); fa[3] += wv * bits2f(u & 0xffff0000u);
        u = v.z; fa[4] += wv * bits2f(u << 16); fa[5] += wv * bits2f(u & 0xffff0000u);
        u = v.w; fa[6] += wv * bits2f(u << 16); fa[7] += wv * bits2f(u & 0xffff0000u);
      }
    }
    // no barrier after h=0: next L0 writes RA; all RA reads completed
    // before barrier (4h) (G3 + hv prefetch); softmax/fts are reg-only.
  }

  const float inv = 1.f / s_run;

  __syncthreads();                                     // (5) parts (G3-h1) reads done
  // ---- fa cross-lane reduce -> parts ----
  {
    #pragma unroll
    for (int k = 0; k < 8; k++) { fa[k] += __shfl_xor(fa[k], 16); fa[k] += __shfl_xor(fa[k], 32); }
    if (lane < 16) {
      #pragma unroll
      for (int k = 0; k < 8; k++) parts[wid][chg * 8 + k] = fa[k];
    }
  }
  __syncthreads();                                     // (6) fts partials ready

  if (t < 128) {
    float fts = parts[0][t] + parts[1][t] + parts[2][t] + parts[3][t];
    *outp = fmaxf(scv + fts * inv, 0.f);
  }
}

// ------------------------------------------------------------------
extern "C" void kernel_launch(void* const* d_in, const int* in_sizes, int n_in,
                              void* d_out, int out_size, void* d_ws, size_t ws_size,
                              hipStream_t stream)
{
  (void)d_ws; (void)ws_size; (void)in_sizes; (void)n_in; (void)out_size;
  const float* feat = (const float*)d_in[0];
  const float *w0 = (const float*)d_in[1],  *g0 = (const float*)d_in[2],  *b0 = (const float*)d_in[3],  *m0 = (const float*)d_in[4],  *v0 = (const float*)d_in[5];
  const float *w1 = (const float*)d_in[6],  *g1 = (const float*)d_in[7],  *b1 = (const float*)d_in[8],  *m1 = (const float*)d_in[9],  *v1 = (const float*)d_in[10];
  const float *w2 = (const float*)d_in[11], *g2 = (const float*)d_in[12], *b2 = (const float*)d_in[13], *m2 = (const float*)d_in[14], *v2 = (const float*)d_in[15];
  const float *wa0= (const float*)d_in[16], *ga = (const float*)d_in[17], *ba = (const float*)d_in[18], *ma = (const float*)d_in[19], *va = (const float*)d_in[20];
  const float *wa1= (const float*)d_in[21], *ba1= (const float*)d_in[22];
  const float *wsc= (const float*)d_in[23], *gsc= (const float*)d_in[24], *bsc= (const float*)d_in[25], *msc= (const float*)d_in[26], *vsc= (const float*)d_in[27];

  k_pre<<<dim3(513), dim3(256), 0, stream>>>(
      feat, w0, g0, b0, m0, v0, w1, g1, b1, m1, v1, w2, g2, b2, m2, v2,
      wa0, ga, ba, ma, va, wa1, ba1, wsc, gsc, bsc, msc, vsc);
  k_main<<<dim3(4096), dim3(256), 0, stream>>>((float*)d_out);
}

// Round 8
// 173.808 us; speedup vs baseline: 1.2767x; 1.2767x over previous
//
#include <hip/hip_runtime.h>

typedef unsigned short u16;
typedef short short8 __attribute__((ext_vector_type(8)));
typedef float floatx4 __attribute__((ext_vector_type(4)));
typedef __bf16 bf16x2 __attribute__((ext_vector_type(2)));

#define MFMA16(a, b, c) __builtin_amdgcn_mfma_f32_16x16x32_bf16((a), (b), (c), 0, 0, 0)

// ---- g_ws byte offsets (256-aligned) ----
#define W1F_OFF   0u         // bf16[4096]
#define B1F_OFF   8192u      // f32[64]
#define W2F_OFF   8448u      // bf16[8192]
#define B2F_OFF   24832u     // f32[128]
#define WA0F_OFF  25344u     // bf16[8192]
#define BAF_OFF   41728u     // f32[64]
#define WA1F_OFF  41984u     // f32[64]
#define BA1F_OFF  42240u     // f32[1]
#define P_OFF     42496u     // f32[32*128*64]
#define Q_OFF     1091072u   // f32[32*128*64]
#define SC_OFF    2139648u   // f32[32*128*128]
#define WS_TOTAL  4236800u

__device__ __align__(256) char g_ws[WS_TOTAL];

__device__ __forceinline__ float bits2f(unsigned u) {
  union { unsigned i; float f; } v; v.i = u; return v.f;
}
__device__ __forceinline__ unsigned f2bits(float f) {
  union { float f; unsigned i; } v; v.f = f; return v.i;
}
__device__ __forceinline__ u16 f2bf(float f) {
  return (u16)((f2bits(f) + 0x8000u) >> 16);
}
// two fp32 -> relu -> packed bf16 pair. gfx950: 2 fmax + 1 v_cvt_pk_bf16_f32.
__device__ __forceinline__ unsigned pack2relu(float a, float b) {
#if __has_builtin(__builtin_amdgcn_cvt_pk_bf16_f32)
  union { bf16x2 h; unsigned u; } cv;
  cv.h = __builtin_amdgcn_cvt_pk_bf16_f32(fmaxf(a, 0.f), fmaxf(b, 0.f));
  return cv.u;
#else
  unsigned lo = (f2bits(fmaxf(a, 0.f)) + 0x8000u) >> 16;
  unsigned hi = (f2bits(fmaxf(b, 0.f)) + 0x8000u) & 0xffff0000u;
  return lo | hi;
#endif
}

// XOR-swizzled LDS addressing (u16 units). Row-major with natural stride,
// 16B chunk index XORed with (row&7) -> conflict-free for all access
// patterns in this kernel (verified per-pattern bank arithmetic).
__device__ __forceinline__ int sw64(int row, int col) {   // 64-col rows
  return (row << 6) + ((((col >> 3) ^ (row & 7)) << 3) | (col & 7));
}
__device__ __forceinline__ int sw128(int row, int col) {  // 128-col rows
  return (row << 7) + ((((col >> 3) ^ (row & 7)) << 3) | (col & 7));
}

// ------------------------------------------------------------------
// k_pre: 513 blocks x 256.  (unchanged)
// ------------------------------------------------------------------
__global__ __launch_bounds__(256) void k_pre(
    const float* __restrict__ feat, const float* __restrict__ w0,
    const float* __restrict__ g0, const float* __restrict__ b0, const float* __restrict__ m0, const float* __restrict__ v0,
    const float* __restrict__ w1, const float* __restrict__ g1, const float* __restrict__ b1, const float* __restrict__ m1, const float* __restrict__ v1,
    const float* __restrict__ w2, const float* __restrict__ g2, const float* __restrict__ b2, const float* __restrict__ m2, const float* __restrict__ v2,
    const float* __restrict__ wa0, const float* __restrict__ ga, const float* __restrict__ ba, const float* __restrict__ ma, const float* __restrict__ va,
    const float* __restrict__ wa1, const float* __restrict__ ba1,
    const float* __restrict__ wsc, const float* __restrict__ gsc, const float* __restrict__ bsc, const float* __restrict__ msc, const float* __restrict__ vsc)
{
  __shared__ float smem[9600];
  const int t = threadIdx.x;
  char* ws = g_ws;
  const int blk = blockIdx.x;

  if (blk == 512) {
    float* fs1 = smem; float* fs2 = smem + 64; float* fsa = smem + 192;
    if (t < 64) {
      float s;
      s = g1[t] * rsqrtf(v1[t] + 1e-5f); fs1[t] = s; ((float*)(ws + B1F_OFF))[t] = b1[t] - m1[t] * s;
      s = ga[t] * rsqrtf(va[t] + 1e-5f); fsa[t] = s; ((float*)(ws + BAF_OFF))[t] = ba[t] - ma[t] * s;
      ((float*)(ws + WA1F_OFF))[t] = wa1[t];
    }
    if (t < 128) { float s = g2[t] * rsqrtf(v2[t] + 1e-5f); fs2[t] = s; ((float*)(ws + B2F_OFF))[t] = b2[t] - m2[t] * s; }
    if (t == 0) ((float*)(ws + BA1F_OFF))[0] = ba1[0];
    __syncthreads();
    u16* W1f = (u16*)(ws + W1F_OFF);
    u16* W2f = (u16*)(ws + W2F_OFF);
    u16* Wa0f = (u16*)(ws + WA0F_OFF);
    for (int i = t; i < 4096; i += 256) W1f[i]  = f2bf(fs1[i >> 6] * w1[i]);
    for (int i = t; i < 8192; i += 256) W2f[i]  = f2bf(fs2[i >> 6] * w2[i]);
    for (int i = t; i < 8192; i += 256) Wa0f[i] = f2bf(fsa[i >> 7] * wa0[i]);
    return;
  }

  const int sub = blk & 255;
  const int b = sub >> 3, n0 = (sub & 7) << 4;
  float* Xs  = smem;          // [64][20]
  float* Wsm = smem + 1280;

  {
    const int c = t >> 2, j = (t & 3) << 2;
    *(float4*)(Xs + c * 20 + j) = *(const float4*)(feat + b * 8192 + c * 128 + n0 + j);
  }

  if (blk < 256) {
    #pragma unroll
    for (int r = 0; r < 8; r++) {
      const int i = (r * 256 + t) * 4;
      float4 v = *(const float4*)(w0 + i);
      const int o = i >> 7, c = i & 127;
      float* d = Wsm + o * 129 + c;
      d[0] = v.x; d[1] = v.y; d[2] = v.z; d[3] = v.w;
    }
    __syncthreads();
    const int o = t & 63, nb = (t >> 6) << 2;
    const float s  = g0[o] * rsqrtf(v0[o] + 1e-5f);
    const float tt = b0[o] - m0[o] * s;
    const float* wr = Wsm + o * 129;
    float dA0=0.f,dA1=0.f,dA2=0.f,dA3=0.f,dB0=0.f,dB1=0.f,dB2=0.f,dB3=0.f;
    #pragma unroll
    for (int c = 0; c < 64; c++) {
      const float a = wr[c], e = wr[64 + c];
      const float4 x = *(const float4*)(Xs + c * 20 + nb);
      dA0 += a * x.x; dA1 += a * x.y; dA2 += a * x.z; dA3 += a * x.w;
      dB0 += e * x.x; dB1 += e * x.y; dB2 += e * x.z; dB3 += e * x.w;
    }
    float* Pp = (float*)(ws + P_OFF) + (b * 128 + n0 + nb) * 64 + o;
    float* Qp = (float*)(ws + Q_OFF) + (b * 128 + n0 + nb) * 64 + o;
    Pp[0]   = s * dB0; Pp[64]  = s * dB1; Pp[128] = s * dB2; Pp[192] = s * dB3;
    Qp[0]   = s * (dA0 - dB0) + tt; Qp[64]  = s * (dA1 - dB1) + tt;
    Qp[128] = s * (dA2 - dB2) + tt; Qp[192] = s * (dA3 - dB3) + tt;
  } else {
    #pragma unroll
    for (int r = 0; r < 8; r++) {
      const int i = (r * 256 + t) * 4;
      float4 v = *(const float4*)(wsc + i);
      const int o = i >> 6, c = i & 63;
      float* d = Wsm + o * 65 + c;
      d[0] = v.x; d[1] = v.y; d[2] = v.z; d[3] = v.w;
    }
    __syncthreads();
    const int o = t & 127, h = (t >> 7) << 3;
    const float s  = gsc[o] * rsqrtf(vsc[o] + 1e-5f);
    const float tt = bsc[o] - msc[o] * s;
    const float* wr = Wsm + o * 65;
    float d0=0.f,d1=0.f,d2=0.f,d3=0.f,d4=0.f,d5=0.f,d6=0.f,d7=0.f;
    #pragma unroll
    for (int c = 0; c < 64; c++) {
      const float a = wr[c];
      const float4 x0 = *(const float4*)(Xs + c * 20 + h);
      const float4 x1 = *(const float4*)(Xs + c * 20 + h + 4);
      d0 += a * x0.x; d1 += a * x0.y; d2 += a * x0.z; d3 += a * x0.w;
      d4 += a * x1.x; d5 += a * x1.y; d6 += a * x1.z; d7 += a * x1.w;
    }
    float* SCp = (float*)(ws + SC_OFF) + (b * 128 + n0 + h) * 128 + o;
    SCp[0]   = s * d0 + tt; SCp[128] = s * d1 + tt; SCp[256] = s * d2 + tt; SCp[384] = s * d3 + tt;
    SCp[512] = s * d4 + tt; SCp[640] = s * d5 + tt; SCp[768] = s * d6 + tt; SCp[896] = s * d7 + tt;
  }
}

// ------------------------------------------------------------------
// k_main R17 = R12 (63.3us known-good) + ONE change: G3 split by
// (att-ch half x edge half). Wave w: att-ch (w&1)*32..+31, edges
// (w>>1)*64..+63.  G3 B-reads 32 -> 16/thread (H2 redundancy 4x->2x),
// logits shfl 16 -> 8.  a3 = 32 VGPRs, loaded after G2's accs die so
// peak live stays in the 128-reg class (R12 measured 60 VGPR+64 AGPR).
// Everything else byte-identical to R12.
// ------------------------------------------------------------------
__global__ __launch_bounds__(256, 4) void k_main(float* __restrict__ out)
{
  __shared__ alignas(16) u16 buf[16384];     // H0@0, H1@8192; H2 overlays @0
  __shared__ float parts[4][128];
  __shared__ float attws[128];

  const int blk = blockIdx.x, b = blk >> 7, n = blk & 127, t = threadIdx.x;
  const char* ws = g_ws;
  const float* Pb  = (const float*)(ws + P_OFF);
  const float* Qb  = (const float*)(ws + Q_OFF);
  const float* SCb = (const float*)(ws + SC_OFF);
  const u16*   W1f = (const u16*)(ws + W1F_OFF);
  const float* b1f = (const float*)(ws + B1F_OFF);
  const u16*   W2f = (const u16*)(ws + W2F_OFF);
  const float* b2f = (const float*)(ws + B2F_OFF);
  const u16*   Wa0f= (const u16*)(ws + WA0F_OFF);
  const float* baf = (const float*)(ws + BAF_OFF);
  const float* wa1f= (const float*)(ws + WA1F_OFF);
  const float  ba1v= *(const float*)(ws + BA1F_OFF);

  u16* H0 = buf;
  u16* H1 = buf + 8192;
  u16* H2 = buf;            // after barrier (3)

  const int lane = t & 63, wid = t >> 6, quad = lane >> 4, l16 = lane & 15;
  const int koff = quad * 8;

  // hoisted A-fragments (no LDS dependence)
  const short8 a1w0 = *(const short8*)(W1f + (wid * 16 + l16) * 64 + koff);
  const short8 a1w1 = *(const short8*)(W1f + (wid * 16 + l16) * 64 + 32 + koff);
  const short8 a2w00 = *(const short8*)(W2f + (wid * 32 + l16) * 64 + koff);
  const short8 a2w01 = *(const short8*)(W2f + (wid * 32 + l16) * 64 + 32 + koff);
  const short8 a2w10 = *(const short8*)(W2f + (wid * 32 + 16 + l16) * 64 + koff);
  const short8 a2w11 = *(const short8*)(W2f + (wid * 32 + 16 + l16) * 64 + 32 + koff);

  // ---- L0: H0[edge][ch] = relu(Q[b,n] + P[b,j]); edge 127 dummy ----
  {
    const int k = t >> 1, half = t & 1;
    const int j = (k < 127) ? ((k < n) ? k : (k + 1)) : n;
    const float4* pr = (const float4*)(Pb + ((b << 7) + j) * 64 + half * 32);
    const float4* qr = (const float4*)(Qb + blk * 64 + half * 32);
    #pragma unroll
    for (int ii = 0; ii < 4; ii++) {
      float4 p0 = pr[2 * ii],     q0 = qr[2 * ii];
      float4 p1 = pr[2 * ii + 1], q1 = qr[2 * ii + 1];
      uint4 sv;
      sv.x = pack2relu(q0.x + p0.x, q0.y + p0.y);
      sv.y = pack2relu(q0.z + p0.z, q0.w + p0.w);
      sv.z = pack2relu(q1.x + p1.x, q1.y + p1.y);
      sv.w = pack2relu(q1.z + p1.z, q1.w + p1.w);
      *(uint4*)(H0 + sw64(k, half * 32 + ii * 8)) = sv;
    }
  }
  __syncthreads();                                           // (1)

  // ---- GEMM1: wave owns rows wid*16..+15 of H1; acc init = bias ----
  {
    const int rr = wid * 16 + quad * 4;
    const float4 bb = *(const float4*)(b1f + rr);
    floatx4 binit; binit[0] = bb.x; binit[1] = bb.y; binit[2] = bb.z; binit[3] = bb.w;
    floatx4 acc[8];
    #pragma unroll
    for (int et = 0; et < 8; et++) acc[et] = binit;
    #pragma unroll
    for (int et = 0; et < 8; et++) {
      const int row = et * 16 + l16;
      short8 bf0 = *(const short8*)(H0 + sw64(row, koff));
      short8 bf1 = *(const short8*)(H0 + sw64(row, koff + 32));
      acc[et] = MFMA16(a1w0, bf0, acc[et]);
      acc[et] = MFMA16(a1w1, bf1, acc[et]);
    }
    #pragma unroll
    for (int et = 0; et < 8; et++) {
      uint2 sv;
      sv.x = pack2relu(acc[et][0], acc[et][1]);
      sv.y = pack2relu(acc[et][2], acc[et][3]);
      *(uint2*)(H1 + sw64(et * 16 + l16, rr)) = sv;
    }
  }
  __syncthreads();                                           // (2)

  // ---- GEMM2: wave owns rows wid*32..+31 of H2; register-staged ----
  {
    const int r2 = wid * 32 + quad * 4;
    const float4 bba = *(const float4*)(b2f + r2);
    const float4 bbb = *(const float4*)(b2f + r2 + 16);
    floatx4 ia; ia[0] = bba.x; ia[1] = bba.y; ia[2] = bba.z; ia[3] = bba.w;
    floatx4 ib; ib[0] = bbb.x; ib[1] = bbb.y; ib[2] = bbb.z; ib[3] = bbb.w;
    floatx4 acc[2][8];
    #pragma unroll
    for (int et = 0; et < 8; et++) { acc[0][et] = ia; acc[1][et] = ib; }
    #pragma unroll
    for (int et = 0; et < 8; et++) {
      const int row = et * 16 + l16;
      short8 bf0 = *(const short8*)(H1 + sw64(row, koff));
      short8 bf1 = *(const short8*)(H1 + sw64(row, koff + 32));
      acc[0][et] = MFMA16(a2w00, bf0, acc[0][et]);
      acc[0][et] = MFMA16(a2w01, bf1, acc[0][et]);
      acc[1][et] = MFMA16(a2w10, bf0, acc[1][et]);
      acc[1][et] = MFMA16(a2w11, bf1, acc[1][et]);
    }
    __syncthreads();                                         // (3) H1 reads done
    #pragma unroll
    for (int m = 0; m < 2; m++) {
      const int rr = r2 + m * 16;
      #pragma unroll
      for (int et = 0; et < 8; et++) {
        uint2 sv;
        sv.x = pack2relu(acc[m][et][0], acc[m][et][1]);
        sv.y = pack2relu(acc[m][et][2], acc[m][et][3]);
        *(uint2*)(H2 + sw128(et * 16 + l16, rr)) = sv;
      }
    }
  }

  // hoisted G3 A-frags: att-ch half (wid&1)*32..+31 (global, L1-hot;
  // issue before the barrier; G2 accs are dead by now)
  const int g3c = (wid & 1) << 5;     // att-ch base
  const int g3e = (wid >> 1) << 6;    // edge base
  short8 a3[2][4];
  #pragma unroll
  for (int m = 0; m < 2; m++)
    #pragma unroll
    for (int ks = 0; ks < 4; ks++)
      a3[m][ks] = *(const short8*)(Wa0f + (g3c + m * 16 + l16) * 128 + ks * 32 + koff);

  __syncthreads();                                           // (4)

  // hoisted epilogue loads (overlap with GEMM3/softmax/fts)
  float scv = 0.f;
  if (t < 128) scv = SCb[blk * 128 + t];
  float* outp = out + ((b << 7) + (t & 127)) * 128 + n;

  // ---- GEMM3 + logits: wave (ch-half, edge-half); partial logits ----
  {
    const float4 bb0 = *(const float4*)(baf + g3c + quad * 4);
    const float4 bb1 = *(const float4*)(baf + g3c + 16 + quad * 4);
    const float4 wv0 = *(const float4*)(wa1f + g3c + quad * 4);
    const float4 wv1 = *(const float4*)(wa1f + g3c + 16 + quad * 4);
    #pragma unroll
    for (int et = 0; et < 4; et++) {
      const int row = g3e + et * 16 + l16;
      short8 bfr[4];
      #pragma unroll
      for (int ks = 0; ks < 4; ks++)
        bfr[ks] = *(const short8*)(H2 + sw128(row, koff + ks * 32));
      floatx4 ac0; ac0[0] = bb0.x; ac0[1] = bb0.y; ac0[2] = bb0.z; ac0[3] = bb0.w;
      floatx4 ac1; ac1[0] = bb1.x; ac1[1] = bb1.y; ac1[2] = bb1.z; ac1[3] = bb1.w;
      #pragma unroll
      for (int ks = 0; ks < 4; ks++) {
        ac0 = MFMA16(a3[0][ks], bfr[ks], ac0);
        ac1 = MFMA16(a3[1][ks], bfr[ks], ac1);
      }
      float p = wv0.x * fmaxf(ac0[0], 0.f) + wv0.y * fmaxf(ac0[1], 0.f)
              + wv0.z * fmaxf(ac0[2], 0.f) + wv0.w * fmaxf(ac0[3], 0.f)
              + wv1.x * fmaxf(ac1[0], 0.f) + wv1.y * fmaxf(ac1[1], 0.f)
              + wv1.z * fmaxf(ac1[2], 0.f) + wv1.w * fmaxf(ac1[3], 0.f);
      p += __shfl_xor(p, 16); p += __shfl_xor(p, 32);
      if (quad == 0) parts[wid][et * 16 + l16] = p;
    }
  }

  // ---- fts prefetch: H2 is final; pull this thread's 8 rows now so the
  //      LDS latency overlaps the softmax barriers ----
  const int chg = t & 15, eg = t >> 4;   // 8 ch x 8 edges per thread
  uint4 hv[8];
  #pragma unroll
  for (int i = 0; i < 8; i++)
    hv[i] = *(const uint4*)(H2 + sw128(eg * 8 + i, chg * 8));

  __syncthreads();                                           // (5)

  // ---- softmax over 127 edges (wave 0) ----
  // logits[e<64] = parts[0]+parts[1]; logits[e>=64] = parts[2]+parts[3]
  if (wid == 0) {
    float a0 = parts[0][lane] + parts[1][lane] + ba1v;
    float a1 = (lane == 63) ? -1e30f
             : (parts[2][lane] + parts[3][lane] + ba1v);
    float mx = fmaxf(a0, a1);
    #pragma unroll
    for (int off = 32; off >= 1; off >>= 1) mx = fmaxf(mx, __shfl_xor(mx, off));
    float e0 = expf(a0 - mx), e1 = expf(a1 - mx);
    float sm = e0 + e1;
    #pragma unroll
    for (int off = 32; off >= 1; off >>= 1) sm += __shfl_xor(sm, off);
    float inv = 1.f / sm;
    attws[lane] = e0 * inv;
    attws[lane + 64] = e1 * inv;   // attw[127] = 0
  }
  __syncthreads();                                           // (6)

  // ---- fts[c] = sum_e attw[e]*H2[e][c]  (H2 values already in hv) ----
  {
    float fa[8];
    #pragma unroll
    for (int k = 0; k < 8; k++) fa[k] = 0.f;
    #pragma unroll
    for (int i = 0; i < 8; i++) {
      const float w = attws[eg * 8 + i];
      uint4 v = hv[i];
      unsigned u;
      u = v.x; fa[0] += w * bits2f(u << 16); fa[1] += w * bits2f(u & 0xffff0000u);
      u = v.y; fa[2] += w * bits2f(u << 16); fa[3] += w * bits2f(u & 0xffff0000u);
      u = v.z; fa[4] += w * bits2f(u << 16); fa[5] += w * bits2f(u & 0xffff0000u);
      u = v.w; fa[6] += w * bits2f(u << 16); fa[7] += w * bits2f(u & 0xffff0000u);
    }
    #pragma unroll
    for (int k = 0; k < 8; k++) { fa[k] += __shfl_xor(fa[k], 16); fa[k] += __shfl_xor(fa[k], 32); }
    if (lane < 16) {
      #pragma unroll
      for (int k = 0; k < 8; k++) parts[wid][chg * 8 + k] = fa[k];
    }
  }
  __syncthreads();                                           // (7)

  if (t < 128) {
    float fts = parts[0][t] + parts[1][t] + parts[2][t] + parts[3][t];
    *outp = fmaxf(scv + fts, 0.f);
  }
}

// ------------------------------------------------------------------
extern "C" void kernel_launch(void* const* d_in, const int* in_sizes, int n_in,
                              void* d_out, int out_size, void* d_ws, size_t ws_size,
                              hipStream_t stream)
{
  (void)d_ws; (void)ws_size; (void)in_sizes; (void)n_in; (void)out_size;
  const float* feat = (const float*)d_in[0];
  const float *w0 = (const float*)d_in[1],  *g0 = (const float*)d_in[2],  *b0 = (const float*)d_in[3],  *m0 = (const float*)d_in[4],  *v0 = (const float*)d_in[5];
  const float *w1 = (const float*)d_in[6],  *g1 = (const float*)d_in[7],  *b1 = (const float*)d_in[8],  *m1 = (const float*)d_in[9],  *v1 = (const float*)d_in[10];
  const float *w2 = (const float*)d_in[11], *g2 = (const float*)d_in[12], *b2 = (const float*)d_in[13], *m2 = (const float*)d_in[14], *v2 = (const float*)d_in[15];
  const float *wa0= (const float*)d_in[16], *ga = (const float*)d_in[17], *ba = (const float*)d_in[18], *ma = (const float*)d_in[19], *va = (const float*)d_in[20];
  const float *wa1= (const float*)d_in[21], *ba1= (const float*)d_in[22];
  const float *wsc= (const float*)d_in[23], *gsc= (const float*)d_in[24], *bsc= (const float*)d_in[25], *msc= (const float*)d_in[26], *vsc= (const float*)d_in[27];

  k_pre<<<dim3(513), dim3(256), 0, stream>>>(
      feat, w0, g0, b0, m0, v0, w1, g1, b1, m1, v1, w2, g2, b2, m2, v2,
      wa0, ga, ba, ma, va, wa1, ba1, wsc, gsc, bsc, msc, vsc);
  k_main<<<dim3(4096), dim3(256), 0, stream>>>((float*)d_out);
}